// Round 15
// baseline (293.812 us; speedup 1.0000x reference)
//
#include <hip/hip_runtime.h>
#include <cstdint>
#include <cstddef>

// ---------------------------------------------------------------------------
// mask_moe: bit-exact vs harness reference (verified r4-r14, absmax 0.0).
// FROZEN arithmetic: partitionable threefry bits, f32 sequential-k FMA dots,
// f32 elementwise chain (softplus/normal/softmax), decision logic.
// Round 15: gating split into K1a (dot chains, 6 threads/row -> 6x wave
// parallelism; each chain is its own single-accumulator ascending-k FMA
// sequence == bit-identical) + K1b (FROZEN epilogue, 1 thread/row).
// All prior gating variants shared 2 waves/SIMD -- the one never-varied
// invariant; this breaks it. Out v3 (r14) + loss kernels untouched.
// ---------------------------------------------------------------------------

namespace {

constexpr int kBH = 256;                  // B*H
constexpr int kL = 512;                   // L
constexpr int kE = 3;                     // experts
constexpr int kRows = kBH * kL;           // 131072 gating rows

__device__ __forceinline__ uint32_t rotl32(uint32_t v, int n) {
  return (v << n) | (v >> (32 - n));
}

// Threefry-2x32, 20 rounds, key = (0, 42)  [jax.random.key(42)]
__device__ __forceinline__ void threefry2x32_k42(uint32_t& x0, uint32_t& x1) {
  const uint32_t ks0 = 0u;
  const uint32_t ks1 = 42u;
  const uint32_t ks2 = 0u ^ 42u ^ 0x1BD11BDAu;
  x0 += ks0; x1 += ks1;
#define TF_ROUND(r) { x0 += x1; x1 = rotl32(x1, (r)); x1 ^= x0; }
  TF_ROUND(13) TF_ROUND(15) TF_ROUND(26) TF_ROUND(6)
  x0 += ks1; x1 += ks2 + 1u;
  TF_ROUND(17) TF_ROUND(29) TF_ROUND(16) TF_ROUND(24)
  x0 += ks2; x1 += ks0 + 2u;
  TF_ROUND(13) TF_ROUND(15) TF_ROUND(26) TF_ROUND(6)
  x0 += ks0; x1 += ks1 + 3u;
  TF_ROUND(17) TF_ROUND(29) TF_ROUND(16) TF_ROUND(24)
  x0 += ks1; x1 += ks2 + 4u;
  TF_ROUND(13) TF_ROUND(15) TF_ROUND(26) TF_ROUND(6)
  x0 += ks2; x1 += ks0 + 5u;
#undef TF_ROUND
}

// partitionable path: bits = x0 ^ x1 of threefry(key, (0, i))
__device__ __forceinline__ uint32_t jax_random_bits(uint32_t flat_idx) {
  uint32_t x0 = 0u;
  uint32_t x1 = flat_idx;
  threefry2x32_k42(x0, x1);
  return x0 ^ x1;
}

// jax.random.normal f32: uniform(-0.99999994, 1.0) then sqrt(2)*erfinv (XLA Giles poly)
__device__ float bits_to_normal(uint32_t bits) {
#pragma clang fp contract(off)
  const uint32_t fb = (bits >> 9) | 0x3F800000u;
  const float f = __uint_as_float(fb) - 1.0f;   // [0, 1)
  const float lo = -0.99999994f;                 // nextafterf(-1, 0)
  float u = f * 2.0f + lo;                       // (maxval-minval) == 2.0f exactly
  u = fmaxf(lo, u);
  float w = -log1pf(-(u * u));
  float p;
  if (w < 5.0f) {
    w = w - 2.5f;
    p = 2.81022636e-08f;
    p = 3.43273939e-07f + p * w;
    p = -3.5233877e-06f + p * w;
    p = -4.39150654e-06f + p * w;
    p = 0.00021858087f + p * w;
    p = -0.00125372503f + p * w;
    p = -0.00417768164f + p * w;
    p = 0.246640727f + p * w;
    p = 1.50140941f + p * w;
  } else {
    w = sqrtf(w) - 3.0f;
    p = -0.000200214257f;
    p = 0.000100950558f + p * w;
    p = 0.00134934322f + p * w;
    p = -0.00367342844f + p * w;
    p = 0.00573950773f + p * w;
    p = -0.0076224613f + p * w;
    p = 0.00943887047f + p * w;
    p = 1.00167406f + p * w;
    p = 2.83297682f + p * w;
  }
  const float einv = p * u;
  return 1.41421354f * einv;  // f32(sqrt(2)) * erfinv(u)
}

// jax.nn.softplus(x) = logaddexp(x, 0) = max(x,0) + log1p(exp(-|x|))
__device__ __forceinline__ float softplus_f32(float v) {
#pragma clang fp contract(off)
  const float amax = fmaxf(v, 0.0f);
  return amax + log1pf(expf(-fabsf(v)));
}

// 4 float4 loads (16 floats) issued back-to-back from pointer P.
#define LD4(B, P, OFF)                                                      \
  _Pragma("unroll")                                                         \
  for (int i_ = 0; i_ < 4; ++i_)                                            \
    B[i_] = *reinterpret_cast<const float4*>((P) + (OFF) + i_ * 4);

// 16 k-steps of one FROZEN ascending-k chain: acc = fmaf(x, w, acc).
#define CH16(XB, WB)                                                        \
  {                                                                         \
    _Pragma("unroll")                                                       \
    for (int j_ = 0; j_ < 4; ++j_) {                                        \
      acc = fmaf(XB[j_].x, WB[j_].x, acc);                                  \
      acc = fmaf(XB[j_].y, WB[j_].y, acc);                                  \
      acc = fmaf(XB[j_].z, WB[j_].z, acc);                                  \
      acc = fmaf(XB[j_].w, WB[j_].w, acc);                                  \
    }                                                                       \
  }

// ---------------------------------------------------------------------------
// Kernel 1a: dot chains. 4096 blocks x 192 threads = 32 rows x 6 chains.
// Thread (row r, chain e): acc = sum_k x[r][k]*w[e][k], single accumulator,
// ascending k, double-buffered 16-k groups for x AND w. Bit-identical to the
// fused 6-chain loop (chains never interacted). Stores fully coalesced:
// acc_out[r*6+chain] == acc_out[blk*192 + t].
// ---------------------------------------------------------------------------
__global__ __launch_bounds__(192) void dot_kernel(
    const float* __restrict__ x, const float* __restrict__ gw,
    const float* __restrict__ nw, float* __restrict__ acc_out) {
  const int t = threadIdx.x;
  const int row_ib = t / 6;            // 0..31
  const int chain = t - row_ib * 6;    // 0..5
  const int r = blockIdx.x * 32 + row_ib;
  const float* xr = x + (size_t)r * kL;
  const float* wr = (chain < 3) ? (gw + chain * kL) : (nw + (chain - 3) * kL);

  float acc = 0.f;
  {
#pragma clang fp contract(off)
    float4 xA[4], xB[4], wA[4], wB[4];
    LD4(xA, xr, 0) LD4(wA, wr, 0)
    for (int k0 = 0; k0 < kL; k0 += 32) {
      LD4(xB, xr, k0 + 16) LD4(wB, wr, k0 + 16)     // prefetch next group
      CH16(xA, wA)
      if (k0 + 32 < kL) { LD4(xA, xr, k0 + 32) LD4(wA, wr, k0 + 32) }
      CH16(xB, wB)
    }
  }
  acc_out[(size_t)blockIdx.x * 192 + t] = acc;   // == acc_out[r*6+chain]
}

// ---------------------------------------------------------------------------
// Kernel 1b: FROZEN epilogue. One thread per row; reads the 6 chain results,
// runs PRNG/softplus/softmax/sort/top-p/entropy exactly as r4-r14.
// ---------------------------------------------------------------------------
__global__ __launch_bounds__(256) void epilogue_kernel(
    const float* __restrict__ acc_in, float* __restrict__ g_out,
    float* __restrict__ kept_out, float* __restrict__ ent_out) {
  const int r = blockIdx.x * 256 + threadIdx.x;
  const float* a = acc_in + (size_t)r * 6;
  float accg[3] = {a[0], a[1], a[2]};
  float accn[3] = {a[3], a[4], a[5]};

  {
#pragma clang fp contract(off)
    float noisy[3];
    const uint32_t nbase = (uint32_t)r * 3u;
#pragma unroll
    for (int e = 0; e < 3; ++e) {
      const float cl = accg[e];
      const float sp = softplus_f32(accn[e]) + 0.01f;  // NOISE_EPS
      const float nz = bits_to_normal(jax_random_bits(nbase + (uint32_t)e));
      const float prod = nz * sp;        // separate rounding: mul then add
      noisy[e] = cl + prod;
    }
    // softmax over 3 experts (f32, max-subtracted)
    const float m = fmaxf(noisy[0], fmaxf(noisy[1], noisy[2]));
    float uu[3];
    uu[0] = expf(noisy[0] - m);
    uu[1] = expf(noisy[1] - m);
    uu[2] = expf(noisy[2] - m);
    const float ssum = (uu[0] + uu[1]) + uu[2];
    float p[3];
    p[0] = uu[0] / ssum;
    p[1] = uu[1] / ssum;
    p[2] = uu[2] / ssum;

    // stable descending argsort of 3
    int o0 = 0;
    if (p[1] > p[o0]) o0 = 1;
    if (p[2] > p[o0]) o0 = 2;
    const int i = (o0 == 0) ? 1 : 0;
    const int j = (o0 == 2) ? 1 : 2;
    const int o1 = (p[j] > p[i]) ? j : i;

    const float s0 = p[o0];
    const float s1 = p[o1];
    const bool keep2 = !(s0 > 0.5f);  // keep top-1 iff s0 > 0.5

    float g[3] = {0.f, 0.f, 0.f};
    g[o0] = 1.f;
    if (keep2) g[o1] = 1.f;

    float ent = 0.f;
    ent += p[0] * logf(p[0] + 1e-10f);
    ent += p[1] * logf(p[1] + 1e-10f);
    ent += p[2] * logf(p[2] + 1e-10f);

    const int bh = r >> 9;
    const int l = r & (kL - 1);
    g_out[r * 3 + 0] = g[0];
    g_out[r * 3 + 1] = g[1];
    g_out[r * 3 + 2] = g[2];
    // kept sorted probs, layout [jpos][l][bh] for coalesced reduction reads
    kept_out[(0 * kL + l) * kBH + bh] = s0;
    kept_out[(1 * kL + l) * kBH + bh] = keep2 ? s1 : 0.f;
    kept_out[(2 * kL + l) * kBH + bh] = 0.f;
    ent_out[r] = -ent;
  }
}

// ---------------------------------------------------------------------------
// Kernel 2a: parallel deterministic partials (r6-proven form).
// ---------------------------------------------------------------------------
__global__ __launch_bounds__(256) void loss_partial_kernel(
    const float* __restrict__ kept, const float* __restrict__ ent,
    double* __restrict__ imp_ws, double* __restrict__ ent_ws) {
  __shared__ double red[256];
  const int t = threadIdx.x;
  const int ln = t & 63;
  const int wg = blockIdx.x * 4 + (t >> 6);   // global wave id, 0..511

  // importance entries
#pragma unroll
  for (int rep = 0; rep < 3; ++rep) {
    const int q = wg + rep * 512;
    const float4 v = reinterpret_cast<const float4*>(kept + (size_t)q * kBH)[ln];
    double s = ((double)v.x + (double)v.y) + ((double)v.z + (double)v.w);
#pragma unroll
    for (int off = 32; off > 0; off >>= 1) s += __shfl_xor(s, off, 64);
    if (ln == 0) imp_ws[q] = s;
  }

  // entropy partial: fixed slice of 1024 rows
  double a = 0.0;
#pragma unroll
  for (int it = 0; it < 4; ++it) {
    a += (double)ent[blockIdx.x * 1024 + it * 256 + t];
  }
  red[t] = a;
  __syncthreads();
  for (int off = 128; off > 0; off >>= 1) {
    if (t < off) red[t] += red[t + off];
    __syncthreads();
  }
  if (t == 0) ent_ws[blockIdx.x] = red[0];
}

// ---------------------------------------------------------------------------
// Kernel 2b: final loss combine (1 block, trivial).
// ---------------------------------------------------------------------------
__global__ __launch_bounds__(256) void loss_final_kernel(
    const double* __restrict__ imp_ws, const double* __restrict__ ent_ws,
    float* __restrict__ loss_out) {
  __shared__ double red[256];
  __shared__ double s_mean;
  const int t = threadIdx.x;

  // mean of importance
  double a = 0.0;
  for (int i = t; i < kL * kE; i += 256) a += imp_ws[i];
  red[t] = a;
  __syncthreads();
  for (int off = 128; off > 0; off >>= 1) {
    if (t < off) red[t] += red[t + off];
    __syncthreads();
  }
  if (t == 0) s_mean = red[0] / (double)(kL * kE);
  __syncthreads();
  const double mean = s_mean;

  // variance (two-pass, ddof=1)
  double sq = 0.0;
  for (int i = t; i < kL * kE; i += 256) {
    const double d = imp_ws[i] - mean;
    sq += d * d;
  }
  red[t] = sq;
  __syncthreads();
  for (int off = 128; off > 0; off >>= 1) {
    if (t < off) red[t] += red[t + off];
    __syncthreads();
  }
  const double var_sum = red[0];
  __syncthreads();

  // entropy total
  double e = 0.0;
  for (int i = t; i < 128; i += 256) e += ent_ws[i];
  red[t] = e;
  __syncthreads();
  for (int off = 128; off > 0; off >>= 1) {
    if (t < off) red[t] += red[t + off];
    __syncthreads();
  }
  if (t == 0) {
    const double var = var_sum / (double)(kL * kE - 1);
    const double loss_imp = var / (mean * mean + 1e-10);
    const double loss_dyn = red[0] / 768.0;  // sum(axis=1).mean() over [BH,E]
    loss_out[0] = (float)(loss_imp + 0.1 * loss_dyn);
  }
}

// ---------------------------------------------------------------------------
// Kernel 3 (v3, r14 form): out[bh, l, d] = g[bh, l, cat(l,d)] + (l==d).
// 16384 blocks x 256 threads; 8 rows/block, 32 threads/row, 64 B/thread.
// ---------------------------------------------------------------------------
__global__ __launch_bounds__(256) void out_kernel(
    const float* __restrict__ g, float* __restrict__ out) {
  const int td = threadIdx.x;
  const int r = blockIdx.x * 8 + (td >> 5);    // 8 rows, 32 threads each
  const int l = r & (kL - 1);
  const float g0 = g[r * 3 + 0];
  const float g1 = g[r * 3 + 1];
  const float g2 = g[r * 3 + 2];
  const int lblk = l >> 6;
  const int loff = l & 63;
  float* orow = out + (size_t)r * kL;
  const int c0 = (td & 31) * 4;
#pragma unroll
  for (int j = 0; j < 4; ++j) {
    const int d0 = c0 + j * 128;
    float vals[4];
#pragma unroll
    for (int k = 0; k < 4; ++k) {
      const int d = d0 + k;
      float v;
      if (((d & 63) == loff) && (d != l)) v = g0;     // S
      else if ((d >> 6) == lblk) v = g1;               // T (includes diagonal)
      else v = g2;                                     // ST
      if (d == l) v += 1.0f;                           // + eye
      vals[k] = v;
    }
    *reinterpret_cast<float4*>(orow + d0) = *reinterpret_cast<float4*>(vals);
  }
}

}  // namespace

extern "C" void kernel_launch(void* const* d_in, const int* in_sizes, int n_in,
                              void* d_out, int out_size, void* d_ws, size_t ws_size,
                              hipStream_t stream) {
  (void)in_sizes; (void)n_in; (void)out_size; (void)ws_size;
  const float* x = (const float*)d_in[0];       // [B,H,L,L] = [32,8,512,512]
  const float* gw = (const float*)d_in[1];      // [3,512]
  const float* nw = (const float*)d_in[2];      // [3,512]
  float* out = (float*)d_out;                   // 64M out + 1 loss

  float* ws = (float*)d_ws;
  float* ws_g = ws;                               // kRows*3 floats
  float* ws_kept = ws + (size_t)kRows * 3;        // kRows*3 floats
  float* ws_ent = ws + (size_t)kRows * 6;         // kRows floats
  float* ws_acc = ws + (size_t)kRows * 7;         // kRows*6 floats
  double* ws_imp = (double*)(ws + (size_t)kRows * 13 + (size_t)kRows);
  // ^ 8B-aligned region after 14k floats (kRows*14 is even -> aligned)
  double* ws_entp = ws_imp + kL * kE;             // 128 doubles

  dot_kernel<<<kRows / 32, 192, 0, stream>>>(x, gw, nw, ws_acc);
  epilogue_kernel<<<kRows / 256, 256, 0, stream>>>(ws_acc, ws_g, ws_kept, ws_ent);
  loss_partial_kernel<<<128, 256, 0, stream>>>(ws_kept, ws_ent, ws_imp, ws_entp);
  loss_final_kernel<<<1, 256, 0, stream>>>(ws_imp, ws_entp,
                                           out + (size_t)kBH * kL * kL);
  out_kernel<<<kRows / 8, 256, 0, stream>>>(ws_g, out);
}

// Round 16
// 124.498 us; speedup vs baseline: 2.3600x; 2.3600x over previous
//
#include <hip/hip_runtime.h>
#include <cstdint>
#include <cstddef>

// ---------------------------------------------------------------------------
// mask_moe: bit-exact vs harness reference (verified r4-r15, absmax 0.0).
// FROZEN arithmetic: partitionable threefry bits, f32 sequential-k FMA dots,
// f32 elementwise chain (softplus/normal/softmax), decision logic.
// Round 16: revert gating to r14/r11 form (r15 chain-split multiplied VMEM
// instrs 6x -> 560 GB/s). Out subsystem: non-temporal stores (L2-policy test;
// out at 4.7 vs fills' 7.0 TB/s, instr overhead ruled out by r14) + merge
// loss_final into out block 0 (4 -> 3 dispatches).
// ---------------------------------------------------------------------------

namespace {

constexpr int kBH = 256;                  // B*H
constexpr int kL = 512;                   // L
constexpr int kE = 3;                     // experts
constexpr int kRows = kBH * kL;           // 131072 gating rows

typedef float v4f __attribute__((ext_vector_type(4)));

__device__ __forceinline__ uint32_t rotl32(uint32_t v, int n) {
  return (v << n) | (v >> (32 - n));
}

// Threefry-2x32, 20 rounds, key = (0, 42)  [jax.random.key(42)]
__device__ __forceinline__ void threefry2x32_k42(uint32_t& x0, uint32_t& x1) {
  const uint32_t ks0 = 0u;
  const uint32_t ks1 = 42u;
  const uint32_t ks2 = 0u ^ 42u ^ 0x1BD11BDAu;
  x0 += ks0; x1 += ks1;
#define TF_ROUND(r) { x0 += x1; x1 = rotl32(x1, (r)); x1 ^= x0; }
  TF_ROUND(13) TF_ROUND(15) TF_ROUND(26) TF_ROUND(6)
  x0 += ks1; x1 += ks2 + 1u;
  TF_ROUND(17) TF_ROUND(29) TF_ROUND(16) TF_ROUND(24)
  x0 += ks2; x1 += ks0 + 2u;
  TF_ROUND(13) TF_ROUND(15) TF_ROUND(26) TF_ROUND(6)
  x0 += ks0; x1 += ks1 + 3u;
  TF_ROUND(17) TF_ROUND(29) TF_ROUND(16) TF_ROUND(24)
  x0 += ks1; x1 += ks2 + 4u;
  TF_ROUND(13) TF_ROUND(15) TF_ROUND(26) TF_ROUND(6)
  x0 += ks2; x1 += ks0 + 5u;
#undef TF_ROUND
}

// partitionable path: bits = x0 ^ x1 of threefry(key, (0, i))
__device__ __forceinline__ uint32_t jax_random_bits(uint32_t flat_idx) {
  uint32_t x0 = 0u;
  uint32_t x1 = flat_idx;
  threefry2x32_k42(x0, x1);
  return x0 ^ x1;
}

// jax.random.normal f32: uniform(-0.99999994, 1.0) then sqrt(2)*erfinv (XLA Giles poly)
__device__ float bits_to_normal(uint32_t bits) {
#pragma clang fp contract(off)
  const uint32_t fb = (bits >> 9) | 0x3F800000u;
  const float f = __uint_as_float(fb) - 1.0f;   // [0, 1)
  const float lo = -0.99999994f;                 // nextafterf(-1, 0)
  float u = f * 2.0f + lo;                       // (maxval-minval) == 2.0f exactly
  u = fmaxf(lo, u);
  float w = -log1pf(-(u * u));
  float p;
  if (w < 5.0f) {
    w = w - 2.5f;
    p = 2.81022636e-08f;
    p = 3.43273939e-07f + p * w;
    p = -3.5233877e-06f + p * w;
    p = -4.39150654e-06f + p * w;
    p = 0.00021858087f + p * w;
    p = -0.00125372503f + p * w;
    p = -0.00417768164f + p * w;
    p = 0.246640727f + p * w;
    p = 1.50140941f + p * w;
  } else {
    w = sqrtf(w) - 3.0f;
    p = -0.000200214257f;
    p = 0.000100950558f + p * w;
    p = 0.00134934322f + p * w;
    p = -0.00367342844f + p * w;
    p = 0.00573950773f + p * w;
    p = -0.0076224613f + p * w;
    p = 0.00943887047f + p * w;
    p = 1.00167406f + p * w;
    p = 2.83297682f + p * w;
  }
  const float einv = p * u;
  return 1.41421354f * einv;  // f32(sqrt(2)) * erfinv(u)
}

// jax.nn.softplus(x) = logaddexp(x, 0) = max(x,0) + log1p(exp(-|x|))
__device__ __forceinline__ float softplus_f32(float v) {
#pragma clang fp contract(off)
  const float amax = fmaxf(v, 0.0f);
  return amax + log1pf(expf(-fabsf(v)));
}

// 4 float4 x-loads (16 k-values) issued back-to-back.
#define LOADG(BUF, OFF)                                                     \
  _Pragma("unroll")                                                         \
  for (int i_ = 0; i_ < 4; ++i_)                                            \
    BUF[i_] = *reinterpret_cast<const float4*>(xr + (OFF) + i_ * 4);

// 16 k-steps of the FROZEN ascending-k FMA sequence; weights via uniform
// global loads (scalar-pipe eligible; gw/nw are const __restrict__).
#define COMP16(BUF, KB)                                                     \
  {                                                                         \
    _Pragma("unroll")                                                       \
    for (int j_ = 0; j_ < 4; ++j_) {                                        \
      const int k_ = (KB) + j_ * 4;                                         \
      const float4 wg0 = *reinterpret_cast<const float4*>(gw + k_);         \
      const float4 wg1 = *reinterpret_cast<const float4*>(gw + kL + k_);    \
      const float4 wg2 = *reinterpret_cast<const float4*>(gw + 2*kL + k_);  \
      const float4 wn0 = *reinterpret_cast<const float4*>(nw + k_);         \
      const float4 wn1 = *reinterpret_cast<const float4*>(nw + kL + k_);    \
      const float4 wn2 = *reinterpret_cast<const float4*>(nw + 2*kL + k_);  \
      const float4 xq = BUF[j_];                                            \
      accg[0] = fmaf(xq.x, wg0.x, accg[0]);                                 \
      accg[1] = fmaf(xq.x, wg1.x, accg[1]);                                 \
      accg[2] = fmaf(xq.x, wg2.x, accg[2]);                                 \
      accn[0] = fmaf(xq.x, wn0.x, accn[0]);                                 \
      accn[1] = fmaf(xq.x, wn1.x, accn[1]);                                 \
      accn[2] = fmaf(xq.x, wn2.x, accn[2]);                                 \
      accg[0] = fmaf(xq.y, wg0.y, accg[0]);                                 \
      accg[1] = fmaf(xq.y, wg1.y, accg[1]);                                 \
      accg[2] = fmaf(xq.y, wg2.y, accg[2]);                                 \
      accn[0] = fmaf(xq.y, wn0.y, accn[0]);                                 \
      accn[1] = fmaf(xq.y, wn1.y, accn[1]);                                 \
      accn[2] = fmaf(xq.y, wn2.y, accn[2]);                                 \
      accg[0] = fmaf(xq.z, wg0.z, accg[0]);                                 \
      accg[1] = fmaf(xq.z, wg1.z, accg[1]);                                 \
      accg[2] = fmaf(xq.z, wg2.z, accg[2]);                                 \
      accn[0] = fmaf(xq.z, wn0.z, accn[0]);                                 \
      accn[1] = fmaf(xq.z, wn1.z, accn[1]);                                 \
      accn[2] = fmaf(xq.z, wn2.z, accn[2]);                                 \
      accg[0] = fmaf(xq.w, wg0.w, accg[0]);                                 \
      accg[1] = fmaf(xq.w, wg1.w, accg[1]);                                 \
      accg[2] = fmaf(xq.w, wg2.w, accg[2]);                                 \
      accn[0] = fmaf(xq.w, wn0.w, accn[0]);                                 \
      accn[1] = fmaf(xq.w, wn1.w, accn[1]);                                 \
      accn[2] = fmaf(xq.w, wn2.w, accn[2]);                                 \
    }                                                                       \
  }

// ---------------------------------------------------------------------------
// Kernel 1: gating (r14/r11 proven form). One thread per row; no LDS. x
// double-buffered in 16-k register groups; weights via uniform global loads.
// FROZEN: f32 sequential-k single-accumulator FMA order per expert.
// ---------------------------------------------------------------------------
__global__ __launch_bounds__(256) void gating_kernel(
    const float* __restrict__ x, const float* __restrict__ gw,
    const float* __restrict__ nw, float* __restrict__ g_out,
    float* __restrict__ kept_out, float* __restrict__ ent_out) {
  const int t = threadIdx.x;
  const int r = blockIdx.x * 256 + t;  // row id in [0, kRows)
  const float* xr = x + (size_t)r * kL;

  float accg[3] = {0.f, 0.f, 0.f};
  float accn[3] = {0.f, 0.f, 0.f};
  {
    float4 bufA[4], bufB[4];
    LOADG(bufA, 0)
    for (int k0 = 0; k0 < kL; k0 += 32) {
      LOADG(bufB, k0 + 16)                       // prefetch next 16-k group
      COMP16(bufA, k0)
      if (k0 + 32 < kL) { LOADG(bufA, k0 + 32) } // prefetch group after
      COMP16(bufB, k0 + 16)
    }
  }

  {
#pragma clang fp contract(off)
    float noisy[3];
    const uint32_t nbase = (uint32_t)r * 3u;
#pragma unroll
    for (int e = 0; e < 3; ++e) {
      const float cl = accg[e];
      const float sp = softplus_f32(accn[e]) + 0.01f;  // NOISE_EPS
      const float nz = bits_to_normal(jax_random_bits(nbase + (uint32_t)e));
      const float prod = nz * sp;        // separate rounding: mul then add
      noisy[e] = cl + prod;
    }
    // softmax over 3 experts (f32, max-subtracted)
    const float m = fmaxf(noisy[0], fmaxf(noisy[1], noisy[2]));
    float uu[3];
    uu[0] = expf(noisy[0] - m);
    uu[1] = expf(noisy[1] - m);
    uu[2] = expf(noisy[2] - m);
    const float ssum = (uu[0] + uu[1]) + uu[2];
    float p[3];
    p[0] = uu[0] / ssum;
    p[1] = uu[1] / ssum;
    p[2] = uu[2] / ssum;

    // stable descending argsort of 3
    int o0 = 0;
    if (p[1] > p[o0]) o0 = 1;
    if (p[2] > p[o0]) o0 = 2;
    const int i = (o0 == 0) ? 1 : 0;
    const int j = (o0 == 2) ? 1 : 2;
    const int o1 = (p[j] > p[i]) ? j : i;

    const float s0 = p[o0];
    const float s1 = p[o1];
    const bool keep2 = !(s0 > 0.5f);  // keep top-1 iff s0 > 0.5

    float g[3] = {0.f, 0.f, 0.f};
    g[o0] = 1.f;
    if (keep2) g[o1] = 1.f;

    float ent = 0.f;
    ent += p[0] * logf(p[0] + 1e-10f);
    ent += p[1] * logf(p[1] + 1e-10f);
    ent += p[2] * logf(p[2] + 1e-10f);

    const int bh = r >> 9;
    const int l = r & (kL - 1);
    g_out[r * 3 + 0] = g[0];
    g_out[r * 3 + 1] = g[1];
    g_out[r * 3 + 2] = g[2];
    // kept sorted probs, layout [jpos][l][bh] for coalesced reduction reads
    kept_out[(0 * kL + l) * kBH + bh] = s0;
    kept_out[(1 * kL + l) * kBH + bh] = keep2 ? s1 : 0.f;
    kept_out[(2 * kL + l) * kBH + bh] = 0.f;
    ent_out[r] = -ent;
  }
}

// ---------------------------------------------------------------------------
// Kernel 2a: parallel deterministic partials (r6-proven form).
// ---------------------------------------------------------------------------
__global__ __launch_bounds__(256) void loss_partial_kernel(
    const float* __restrict__ kept, const float* __restrict__ ent,
    double* __restrict__ imp_ws, double* __restrict__ ent_ws) {
  __shared__ double red[256];
  const int t = threadIdx.x;
  const int ln = t & 63;
  const int wg = blockIdx.x * 4 + (t >> 6);   // global wave id, 0..511

  // importance entries
#pragma unroll
  for (int rep = 0; rep < 3; ++rep) {
    const int q = wg + rep * 512;
    const float4 v = reinterpret_cast<const float4*>(kept + (size_t)q * kBH)[ln];
    double s = ((double)v.x + (double)v.y) + ((double)v.z + (double)v.w);
#pragma unroll
    for (int off = 32; off > 0; off >>= 1) s += __shfl_xor(s, off, 64);
    if (ln == 0) imp_ws[q] = s;
  }

  // entropy partial: fixed slice of 1024 rows
  double a = 0.0;
#pragma unroll
  for (int it = 0; it < 4; ++it) {
    a += (double)ent[blockIdx.x * 1024 + it * 256 + t];
  }
  red[t] = a;
  __syncthreads();
  for (int off = 128; off > 0; off >>= 1) {
    if (t < off) red[t] += red[t + off];
    __syncthreads();
  }
  if (t == 0) ent_ws[blockIdx.x] = red[0];
}

// ---------------------------------------------------------------------------
// Kernel 3 (fused): block 0 computes final loss (r14 loss_final body);
// all blocks write out[bh, l, d] = g[bh, l, cat(l,d)] + (l==d) with
// NON-TEMPORAL float4 stores (L2-policy test: write-once 256 MB stream).
// 16384 blocks x 256 threads; 8 rows/block, 32 threads/row, 64 B/thread.
// ---------------------------------------------------------------------------
__global__ __launch_bounds__(256) void out_kernel(
    const float* __restrict__ g, const double* __restrict__ imp_ws,
    const double* __restrict__ ent_ws, float* __restrict__ out,
    float* __restrict__ loss_out) {
  const int td = threadIdx.x;

  if (blockIdx.x == 0) {
    // final loss combine (identical math/order to r14 loss_final_kernel)
    __shared__ double red[256];
    __shared__ double s_mean;
    double a = 0.0;
    for (int i = td; i < kL * kE; i += 256) a += imp_ws[i];
    red[td] = a;
    __syncthreads();
    for (int off = 128; off > 0; off >>= 1) {
      if (td < off) red[td] += red[td + off];
      __syncthreads();
    }
    if (td == 0) s_mean = red[0] / (double)(kL * kE);
    __syncthreads();
    const double mean = s_mean;

    double sq = 0.0;
    for (int i = td; i < kL * kE; i += 256) {
      const double d = imp_ws[i] - mean;
      sq += d * d;
    }
    red[td] = sq;
    __syncthreads();
    for (int off = 128; off > 0; off >>= 1) {
      if (td < off) red[td] += red[td + off];
      __syncthreads();
    }
    const double var_sum = red[0];
    __syncthreads();

    double e = 0.0;
    for (int i = td; i < 128; i += 256) e += ent_ws[i];
    red[td] = e;
    __syncthreads();
    for (int off = 128; off > 0; off >>= 1) {
      if (td < off) red[td] += red[td + off];
      __syncthreads();
    }
    if (td == 0) {
      const double var = var_sum / (double)(kL * kE - 1);
      const double loss_imp = var / (mean * mean + 1e-10);
      const double loss_dyn = red[0] / 768.0;
      loss_out[0] = (float)(loss_imp + 0.1 * loss_dyn);
    }
  }

  const int r = blockIdx.x * 8 + (td >> 5);    // 8 rows, 32 threads each
  const int l = r & (kL - 1);
  const float g0 = g[r * 3 + 0];
  const float g1 = g[r * 3 + 1];
  const float g2 = g[r * 3 + 2];
  const int lblk = l >> 6;
  const int loff = l & 63;
  float* orow = out + (size_t)r * kL;
  const int c0 = (td & 31) * 4;
#pragma unroll
  for (int j = 0; j < 4; ++j) {
    const int d0 = c0 + j * 128;
    v4f vals;
#pragma unroll
    for (int k = 0; k < 4; ++k) {
      const int d = d0 + k;
      float v;
      if (((d & 63) == loff) && (d != l)) v = g0;     // S
      else if ((d >> 6) == lblk) v = g1;               // T (includes diagonal)
      else v = g2;                                     // ST
      if (d == l) v += 1.0f;                           // + eye
      vals[k] = v;
    }
    __builtin_nontemporal_store(vals, reinterpret_cast<v4f*>(orow + d0));
  }
}

}  // namespace

extern "C" void kernel_launch(void* const* d_in, const int* in_sizes, int n_in,
                              void* d_out, int out_size, void* d_ws, size_t ws_size,
                              hipStream_t stream) {
  (void)in_sizes; (void)n_in; (void)out_size; (void)ws_size;
  const float* x = (const float*)d_in[0];       // [B,H,L,L] = [32,8,512,512]
  const float* gw = (const float*)d_in[1];      // [3,512]
  const float* nw = (const float*)d_in[2];      // [3,512]
  float* out = (float*)d_out;                   // 64M out + 1 loss

  float* ws = (float*)d_ws;
  float* ws_g = ws;                               // kRows*3 floats
  float* ws_kept = ws + (size_t)kRows * 3;        // kRows*3 floats
  float* ws_ent = ws + (size_t)kRows * 6;         // kRows floats
  double* ws_imp = (double*)(ws + (size_t)kRows * 7);   // 1536 doubles (8B-aligned)
  double* ws_entp = ws_imp + kL * kE;                   // 128 doubles

  gating_kernel<<<kRows / 256, 256, 0, stream>>>(x, gw, nw, ws_g, ws_kept, ws_ent);
  loss_partial_kernel<<<128, 256, 0, stream>>>(ws_kept, ws_ent, ws_imp, ws_entp);
  out_kernel<<<kRows / 8, 256, 0, stream>>>(ws_g, ws_imp, ws_entp, out,
                                            out + (size_t)kBH * kL * kL);
}

// Round 17
// 114.795 us; speedup vs baseline: 2.5595x; 1.0845x over previous
//
#include <hip/hip_runtime.h>
#include <cstdint>
#include <cstddef>

// ---------------------------------------------------------------------------
// mask_moe: bit-exact vs harness reference (verified r4-r16, absmax 0.0).
// FROZEN arithmetic: partitionable threefry bits, f32 sequential-k FMA dots,
// f32 elementwise chain (softplus/normal/softmax), decision logic.
// Round 17: gating LDS-v2 = r6's coalesced staging + r11's uniform weights,
// with r6's two flaws fixed: pad-36 aligned ds_read_b128 x-reads (vs pad-65
// scalar b32) and NO LDS weight reads. Double-buffered 32-col tiles, one
// barrier/tile, loads issued before compute (T14 split). Out (NT stores,
// merged loss-final) and loss kernels: r16 byte-identical.
// ---------------------------------------------------------------------------

namespace {

constexpr int kBH = 256;                  // B*H
constexpr int kL = 512;                   // L
constexpr int kE = 3;                     // experts
constexpr int kRows = kBH * kL;           // 131072 gating rows
constexpr int kPad = 36;                  // LDS row stride (floats): 144 B,
                                          // 16B-aligned, 2-way banks (free)

typedef float v4f __attribute__((ext_vector_type(4)));

__device__ __forceinline__ uint32_t rotl32(uint32_t v, int n) {
  return (v << n) | (v >> (32 - n));
}

// Threefry-2x32, 20 rounds, key = (0, 42)  [jax.random.key(42)]
__device__ __forceinline__ void threefry2x32_k42(uint32_t& x0, uint32_t& x1) {
  const uint32_t ks0 = 0u;
  const uint32_t ks1 = 42u;
  const uint32_t ks2 = 0u ^ 42u ^ 0x1BD11BDAu;
  x0 += ks0; x1 += ks1;
#define TF_ROUND(r) { x0 += x1; x1 = rotl32(x1, (r)); x1 ^= x0; }
  TF_ROUND(13) TF_ROUND(15) TF_ROUND(26) TF_ROUND(6)
  x0 += ks1; x1 += ks2 + 1u;
  TF_ROUND(17) TF_ROUND(29) TF_ROUND(16) TF_ROUND(24)
  x0 += ks2; x1 += ks0 + 2u;
  TF_ROUND(13) TF_ROUND(15) TF_ROUND(26) TF_ROUND(6)
  x0 += ks0; x1 += ks1 + 3u;
  TF_ROUND(17) TF_ROUND(29) TF_ROUND(16) TF_ROUND(24)
  x0 += ks1; x1 += ks2 + 4u;
  TF_ROUND(13) TF_ROUND(15) TF_ROUND(26) TF_ROUND(6)
  x0 += ks2; x1 += ks0 + 5u;
#undef TF_ROUND
}

// partitionable path: bits = x0 ^ x1 of threefry(key, (0, i))
__device__ __forceinline__ uint32_t jax_random_bits(uint32_t flat_idx) {
  uint32_t x0 = 0u;
  uint32_t x1 = flat_idx;
  threefry2x32_k42(x0, x1);
  return x0 ^ x1;
}

// jax.random.normal f32: uniform(-0.99999994, 1.0) then sqrt(2)*erfinv (XLA Giles poly)
__device__ float bits_to_normal(uint32_t bits) {
#pragma clang fp contract(off)
  const uint32_t fb = (bits >> 9) | 0x3F800000u;
  const float f = __uint_as_float(fb) - 1.0f;   // [0, 1)
  const float lo = -0.99999994f;                 // nextafterf(-1, 0)
  float u = f * 2.0f + lo;                       // (maxval-minval) == 2.0f exactly
  u = fmaxf(lo, u);
  float w = -log1pf(-(u * u));
  float p;
  if (w < 5.0f) {
    w = w - 2.5f;
    p = 2.81022636e-08f;
    p = 3.43273939e-07f + p * w;
    p = -3.5233877e-06f + p * w;
    p = -4.39150654e-06f + p * w;
    p = 0.00021858087f + p * w;
    p = -0.00125372503f + p * w;
    p = -0.00417768164f + p * w;
    p = 0.246640727f + p * w;
    p = 1.50140941f + p * w;
  } else {
    w = sqrtf(w) - 3.0f;
    p = -0.000200214257f;
    p = 0.000100950558f + p * w;
    p = 0.00134934322f + p * w;
    p = -0.00367342844f + p * w;
    p = 0.00573950773f + p * w;
    p = -0.0076224613f + p * w;
    p = 0.00943887047f + p * w;
    p = 1.00167406f + p * w;
    p = 2.83297682f + p * w;
  }
  const float einv = p * u;
  return 1.41421354f * einv;  // f32(sqrt(2)) * erfinv(u)
}

// jax.nn.softplus(x) = logaddexp(x, 0) = max(x,0) + log1p(exp(-|x|))
__device__ __forceinline__ float softplus_f32(float v) {
#pragma clang fp contract(off)
  const float amax = fmaxf(v, 0.0f);
  return amax + log1pf(expf(-fabsf(v)));
}

// 16 k-steps of the FROZEN ascending-k FMA sequence; weights via uniform
// global loads (scalar-pipe eligible; gw/nw are const __restrict__).
#define COMP16(BUF, KB)                                                     \
  {                                                                         \
    _Pragma("unroll")                                                       \
    for (int j_ = 0; j_ < 4; ++j_) {                                        \
      const int k_ = (KB) + j_ * 4;                                         \
      const float4 wg0 = *reinterpret_cast<const float4*>(gw + k_);         \
      const float4 wg1 = *reinterpret_cast<const float4*>(gw + kL + k_);    \
      const float4 wg2 = *reinterpret_cast<const float4*>(gw + 2*kL + k_);  \
      const float4 wn0 = *reinterpret_cast<const float4*>(nw + k_);         \
      const float4 wn1 = *reinterpret_cast<const float4*>(nw + kL + k_);    \
      const float4 wn2 = *reinterpret_cast<const float4*>(nw + 2*kL + k_);  \
      const float4 xq = BUF[j_];                                            \
      accg[0] = fmaf(xq.x, wg0.x, accg[0]);                                 \
      accg[1] = fmaf(xq.x, wg1.x, accg[1]);                                 \
      accg[2] = fmaf(xq.x, wg2.x, accg[2]);                                 \
      accn[0] = fmaf(xq.x, wn0.x, accn[0]);                                 \
      accn[1] = fmaf(xq.x, wn1.x, accn[1]);                                 \
      accn[2] = fmaf(xq.x, wn2.x, accn[2]);                                 \
      accg[0] = fmaf(xq.y, wg0.y, accg[0]);                                 \
      accg[1] = fmaf(xq.y, wg1.y, accg[1]);                                 \
      accg[2] = fmaf(xq.y, wg2.y, accg[2]);                                 \
      accn[0] = fmaf(xq.y, wn0.y, accn[0]);                                 \
      accn[1] = fmaf(xq.y, wn1.y, accn[1]);                                 \
      accn[2] = fmaf(xq.y, wn2.y, accn[2]);                                 \
      accg[0] = fmaf(xq.z, wg0.z, accg[0]);                                 \
      accg[1] = fmaf(xq.z, wg1.z, accg[1]);                                 \
      accg[2] = fmaf(xq.z, wg2.z, accg[2]);                                 \
      accn[0] = fmaf(xq.z, wn0.z, accn[0]);                                 \
      accn[1] = fmaf(xq.z, wn1.z, accn[1]);                                 \
      accn[2] = fmaf(xq.z, wn2.z, accn[2]);                                 \
      accg[0] = fmaf(xq.w, wg0.w, accg[0]);                                 \
      accg[1] = fmaf(xq.w, wg1.w, accg[1]);                                 \
      accg[2] = fmaf(xq.w, wg2.w, accg[2]);                                 \
      accn[0] = fmaf(xq.w, wn0.w, accn[0]);                                 \
      accn[1] = fmaf(xq.w, wn1.w, accn[1]);                                 \
      accn[2] = fmaf(xq.w, wn2.w, accn[2]);                                 \
    }                                                                       \
  }

// cooperative tile load: thread t grabs 8 float4s of tile cols [K0,K0+32)
// (fi = i*256+t -> row fi/8, col-quad fi%8; per instr: 8 x 128B segments)
#define STAGE_LOAD(ST, K0)                                                  \
  _Pragma("unroll")                                                         \
  for (int i_ = 0; i_ < 8; ++i_) {                                          \
    const int fi_ = i_ * 256 + t;                                           \
    const int row_ = fi_ >> 3;                                              \
    const int c4_ = fi_ & 7;                                                \
    ST[i_] = *reinterpret_cast<const float4*>(                              \
        xblk + (size_t)row_ * kL + (K0) + c4_ * 4);                         \
  }

#define STAGE_WRITE(ST, BUF)                                                \
  _Pragma("unroll")                                                         \
  for (int i_ = 0; i_ < 8; ++i_) {                                          \
    const int fi_ = i_ * 256 + t;                                           \
    const int row_ = fi_ >> 3;                                              \
    const int c4_ = fi_ & 7;                                                \
    *reinterpret_cast<float4*>(&s_x[BUF][row_ * kPad + c4_ * 4]) = ST[i_];  \
  }

// ---------------------------------------------------------------------------
// Kernel 1: gating (LDS-v2). One thread per row; x staged via double-buffered
// 256x32 LDS tiles (coalesced global loads, aligned b128 LDS reads); weights
// via uniform global loads. FROZEN f32 sequential-k FMA order per expert.
// ---------------------------------------------------------------------------
__global__ __launch_bounds__(256) void gating_kernel(
    const float* __restrict__ x, const float* __restrict__ gw,
    const float* __restrict__ nw, float* __restrict__ g_out,
    float* __restrict__ kept_out, float* __restrict__ ent_out) {
  __shared__ float s_x[2][256 * kPad];   // 2 x 36,864 B
  const int t = threadIdx.x;
  const int r = blockIdx.x * 256 + t;    // this thread's row
  const float* xblk = x + (size_t)blockIdx.x * 256 * kL;

  // prologue: stage tile 0
  {
    float4 st[8];
    STAGE_LOAD(st, 0)
    STAGE_WRITE(st, 0)
  }
  __syncthreads();

  float accg[3] = {0.f, 0.f, 0.f};
  float accn[3] = {0.f, 0.f, 0.f};
  for (int tile = 0; tile < 16; ++tile) {
    const int k0 = tile * 32;
    float4 st[8];
    if (tile < 15) { STAGE_LOAD(st, k0 + 32) }   // issue next tile's loads
    {
#pragma clang fp contract(off)
      const float* xrow = &s_x[tile & 1][t * kPad];
      float4 bufL[4];
      bufL[0] = *reinterpret_cast<const float4*>(xrow);
      bufL[1] = *reinterpret_cast<const float4*>(xrow + 4);
      bufL[2] = *reinterpret_cast<const float4*>(xrow + 8);
      bufL[3] = *reinterpret_cast<const float4*>(xrow + 12);
      COMP16(bufL, k0)
      bufL[0] = *reinterpret_cast<const float4*>(xrow + 16);
      bufL[1] = *reinterpret_cast<const float4*>(xrow + 20);
      bufL[2] = *reinterpret_cast<const float4*>(xrow + 24);
      bufL[3] = *reinterpret_cast<const float4*>(xrow + 28);
      COMP16(bufL, k0 + 16)
    }
    if (tile < 15) { STAGE_WRITE(st, (tile + 1) & 1) }
    __syncthreads();
  }

  {
#pragma clang fp contract(off)
    float noisy[3];
    const uint32_t nbase = (uint32_t)r * 3u;
#pragma unroll
    for (int e = 0; e < 3; ++e) {
      const float cl = accg[e];
      const float sp = softplus_f32(accn[e]) + 0.01f;  // NOISE_EPS
      const float nz = bits_to_normal(jax_random_bits(nbase + (uint32_t)e));
      const float prod = nz * sp;        // separate rounding: mul then add
      noisy[e] = cl + prod;
    }
    // softmax over 3 experts (f32, max-subtracted)
    const float m = fmaxf(noisy[0], fmaxf(noisy[1], noisy[2]));
    float uu[3];
    uu[0] = expf(noisy[0] - m);
    uu[1] = expf(noisy[1] - m);
    uu[2] = expf(noisy[2] - m);
    const float ssum = (uu[0] + uu[1]) + uu[2];
    float p[3];
    p[0] = uu[0] / ssum;
    p[1] = uu[1] / ssum;
    p[2] = uu[2] / ssum;

    // stable descending argsort of 3
    int o0 = 0;
    if (p[1] > p[o0]) o0 = 1;
    if (p[2] > p[o0]) o0 = 2;
    const int i = (o0 == 0) ? 1 : 0;
    const int j = (o0 == 2) ? 1 : 2;
    const int o1 = (p[j] > p[i]) ? j : i;

    const float s0 = p[o0];
    const float s1 = p[o1];
    const bool keep2 = !(s0 > 0.5f);  // keep top-1 iff s0 > 0.5

    float g[3] = {0.f, 0.f, 0.f};
    g[o0] = 1.f;
    if (keep2) g[o1] = 1.f;

    float ent = 0.f;
    ent += p[0] * logf(p[0] + 1e-10f);
    ent += p[1] * logf(p[1] + 1e-10f);
    ent += p[2] * logf(p[2] + 1e-10f);

    const int bh = r >> 9;
    const int l = r & (kL - 1);
    g_out[r * 3 + 0] = g[0];
    g_out[r * 3 + 1] = g[1];
    g_out[r * 3 + 2] = g[2];
    // kept sorted probs, layout [jpos][l][bh] for coalesced reduction reads
    kept_out[(0 * kL + l) * kBH + bh] = s0;
    kept_out[(1 * kL + l) * kBH + bh] = keep2 ? s1 : 0.f;
    kept_out[(2 * kL + l) * kBH + bh] = 0.f;
    ent_out[r] = -ent;
  }
}

// ---------------------------------------------------------------------------
// Kernel 2a: parallel deterministic partials (r6-proven form).
// ---------------------------------------------------------------------------
__global__ __launch_bounds__(256) void loss_partial_kernel(
    const float* __restrict__ kept, const float* __restrict__ ent,
    double* __restrict__ imp_ws, double* __restrict__ ent_ws) {
  __shared__ double red[256];
  const int t = threadIdx.x;
  const int ln = t & 63;
  const int wg = blockIdx.x * 4 + (t >> 6);   // global wave id, 0..511

  // importance entries
#pragma unroll
  for (int rep = 0; rep < 3; ++rep) {
    const int q = wg + rep * 512;
    const float4 v = reinterpret_cast<const float4*>(kept + (size_t)q * kBH)[ln];
    double s = ((double)v.x + (double)v.y) + ((double)v.z + (double)v.w);
#pragma unroll
    for (int off = 32; off > 0; off >>= 1) s += __shfl_xor(s, off, 64);
    if (ln == 0) imp_ws[q] = s;
  }

  // entropy partial: fixed slice of 1024 rows
  double a = 0.0;
#pragma unroll
  for (int it = 0; it < 4; ++it) {
    a += (double)ent[blockIdx.x * 1024 + it * 256 + t];
  }
  red[t] = a;
  __syncthreads();
  for (int off = 128; off > 0; off >>= 1) {
    if (t < off) red[t] += red[t + off];
    __syncthreads();
  }
  if (t == 0) ent_ws[blockIdx.x] = red[0];
}

// ---------------------------------------------------------------------------
// Kernel 3 (fused, r16 form): block 0 computes final loss; all blocks write
// out with NON-TEMPORAL float4 stores. 16384 x 256; 8 rows/block.
// ---------------------------------------------------------------------------
__global__ __launch_bounds__(256) void out_kernel(
    const float* __restrict__ g, const double* __restrict__ imp_ws,
    const double* __restrict__ ent_ws, float* __restrict__ out,
    float* __restrict__ loss_out) {
  const int td = threadIdx.x;

  if (blockIdx.x == 0) {
    // final loss combine (identical math/order to r14 loss_final_kernel)
    __shared__ double red[256];
    __shared__ double s_mean;
    double a = 0.0;
    for (int i = td; i < kL * kE; i += 256) a += imp_ws[i];
    red[td] = a;
    __syncthreads();
    for (int off = 128; off > 0; off >>= 1) {
      if (td < off) red[td] += red[td + off];
      __syncthreads();
    }
    if (td == 0) s_mean = red[0] / (double)(kL * kE);
    __syncthreads();
    const double mean = s_mean;

    double sq = 0.0;
    for (int i = td; i < kL * kE; i += 256) {
      const double d = imp_ws[i] - mean;
      sq += d * d;
    }
    red[td] = sq;
    __syncthreads();
    for (int off = 128; off > 0; off >>= 1) {
      if (td < off) red[td] += red[td + off];
      __syncthreads();
    }
    const double var_sum = red[0];
    __syncthreads();

    double e = 0.0;
    for (int i = td; i < 128; i += 256) e += ent_ws[i];
    red[td] = e;
    __syncthreads();
    for (int off = 128; off > 0; off >>= 1) {
      if (td < off) red[td] += red[td + off];
      __syncthreads();
    }
    if (td == 0) {
      const double var = var_sum / (double)(kL * kE - 1);
      const double loss_imp = var / (mean * mean + 1e-10);
      const double loss_dyn = red[0] / 768.0;
      loss_out[0] = (float)(loss_imp + 0.1 * loss_dyn);
    }
  }

  const int r = blockIdx.x * 8 + (td >> 5);    // 8 rows, 32 threads each
  const int l = r & (kL - 1);
  const float g0 = g[r * 3 + 0];
  const float g1 = g[r * 3 + 1];
  const float g2 = g[r * 3 + 2];
  const int lblk = l >> 6;
  const int loff = l & 63;
  float* orow = out + (size_t)r * kL;
  const int c0 = (td & 31) * 4;
#pragma unroll
  for (int j = 0; j < 4; ++j) {
    const int d0 = c0 + j * 128;
    v4f vals;
#pragma unroll
    for (int k = 0; k < 4; ++k) {
      const int d = d0 + k;
      float v;
      if (((d & 63) == loff) && (d != l)) v = g0;     // S
      else if ((d >> 6) == lblk) v = g1;               // T (includes diagonal)
      else v = g2;                                     // ST
      if (d == l) v += 1.0f;                           // + eye
      vals[k] = v;
    }
    __builtin_nontemporal_store(vals, reinterpret_cast<v4f*>(orow + d0));
  }
}

}  // namespace

extern "C" void kernel_launch(void* const* d_in, const int* in_sizes, int n_in,
                              void* d_out, int out_size, void* d_ws, size_t ws_size,
                              hipStream_t stream) {
  (void)in_sizes; (void)n_in; (void)out_size; (void)ws_size;
  const float* x = (const float*)d_in[0];       // [B,H,L,L] = [32,8,512,512]
  const float* gw = (const float*)d_in[1];      // [3,512]
  const float* nw = (const float*)d_in[2];      // [3,512]
  float* out = (float*)d_out;                   // 64M out + 1 loss

  float* ws = (float*)d_ws;
  float* ws_g = ws;                               // kRows*3 floats
  float* ws_kept = ws + (size_t)kRows * 3;        // kRows*3 floats
  float* ws_ent = ws + (size_t)kRows * 6;         // kRows floats
  double* ws_imp = (double*)(ws + (size_t)kRows * 7);   // 1536 doubles (8B-aligned)
  double* ws_entp = ws_imp + kL * kE;                   // 128 doubles

  gating_kernel<<<kRows / 256, 256, 0, stream>>>(x, gw, nw, ws_g, ws_kept, ws_ent);
  loss_partial_kernel<<<128, 256, 0, stream>>>(ws_kept, ws_ent, ws_imp, ws_entp);
  out_kernel<<<kRows / 8, 256, 0, stream>>>(ws_g, ws_imp, ws_entp, out,
                                            out + (size_t)kBH * kL * kL);
}